// Round 1
// baseline (832.965 us; speedup 1.0000x reference)
//
#include <hip/hip_runtime.h>

#define B_N 100000
#define U_N 50000
#define F_N 512
#define D_N 128
#define K_N 10
#define M1  150000   // B_N + U_N
#define K1  512
#define K2  1152     // 2F + D

typedef __attribute__((ext_vector_type(8))) short bf16x8;
typedef __attribute__((ext_vector_type(4))) float f32x4;

#define BK 32
#define LDS_STRIDE 56   // ushorts; 112B row stride: 16B-aligned, banks spread

static __device__ __forceinline__ ushort f2bf(float f) {
  union { float f; unsigned u; } x; x.f = f;
  unsigned r = x.u + 0x7fffu + ((x.u >> 16) & 1u);
  return (ushort)(r >> 16);
}

__global__ void prep_transpose_bf16(const float* __restrict__ src,
                                    ushort* __restrict__ dst, int K, int N) {
  int idx = blockIdx.x * 256 + threadIdx.x;
  if (idx >= K * N) return;
  int k = idx / N, n = idx % N;
  dst[(size_t)n * K + k] = f2bf(src[idx]);
}

// GEMM1: h[150000][128] = concat(fb, fn) @ W   (+ fused p/q row-dot epilogue)
__launch_bounds__(256, 2)
__global__ void gemm1(const float* __restrict__ fb, const float* __restrict__ fn,
                      const ushort* __restrict__ Wt, const float* __restrict__ avec,
                      float* __restrict__ h, float* __restrict__ p,
                      float* __restrict__ q) {
  __shared__ ushort As[128 * LDS_STRIDE];
  const int tid  = threadIdx.x;
  const int lane = tid & 63;
  const int wv   = tid >> 6;
  const int row0 = blockIdx.x * 128;
  const int l15 = lane & 15;
  const int l4  = lane >> 4;

  f32x4 acc[2][8];
  #pragma unroll
  for (int m = 0; m < 2; m++)
    #pragma unroll
    for (int n = 0; n < 8; n++) acc[m][n] = (f32x4)0.0f;

  for (int kt = 0; kt < K1 / BK; ++kt) {
    const int k0 = kt * BK;
    __syncthreads();
    // stage A tile: 128 rows x 32 k, fp32 -> bf16
    #pragma unroll
    for (int i = 0; i < 4; ++i) {
      int lin = tid + i * 256;   // 0..1023
      int r   = lin >> 3;
      int qd  = lin & 7;
      int gr  = row0 + r;
      ushort4 ov;
      if (gr < M1) {
        const float* src = (gr < B_N) ? (fb + (size_t)gr * F_N)
                                      : (fn + (size_t)(gr - B_N) * F_N);
        float4 v = *reinterpret_cast<const float4*>(src + k0 + qd * 4);
        ov.x = f2bf(v.x); ov.y = f2bf(v.y); ov.z = f2bf(v.z); ov.w = f2bf(v.w);
      } else {
        ov = make_ushort4(0, 0, 0, 0);
      }
      *reinterpret_cast<ushort4*>(&As[r * LDS_STRIDE + qd * 4]) = ov;
    }
    __syncthreads();

    bf16x8 af[2];
    #pragma unroll
    for (int m = 0; m < 2; m++) {
      int r = wv * 32 + m * 16 + l15;
      af[m] = *reinterpret_cast<const bf16x8*>(&As[r * LDS_STRIDE + l4 * 8]);
    }
    #pragma unroll
    for (int n = 0; n < 8; n++) {
      int c = n * 16 + l15;
      bf16x8 bfr = *reinterpret_cast<const bf16x8*>(Wt + (size_t)c * K1 + k0 + l4 * 8);
      acc[0][n] = __builtin_amdgcn_mfma_f32_16x16x32_bf16(af[0], bfr, acc[0][n], 0, 0, 0);
      acc[1][n] = __builtin_amdgcn_mfma_f32_16x16x32_bf16(af[1], bfr, acc[1][n], 0, 0, 0);
    }
  }

  // epilogue: store h, fused p/q dot with a-vector halves
  float av0[8], av1[8];
  #pragma unroll
  for (int n = 0; n < 8; n++) {
    av0[n] = avec[n * 16 + l15];
    av1[n] = avec[128 + n * 16 + l15];
  }
  #pragma unroll
  for (int m = 0; m < 2; m++) {
    #pragma unroll
    for (int j = 0; j < 4; j++) {
      int r = row0 + wv * 32 + m * 16 + l4 * 4 + j;
      bool ok = r < M1;
      float dot = 0.f;
      #pragma unroll
      for (int n = 0; n < 8; n++) {
        float v = acc[m][n][j];
        if (ok) h[(size_t)r * D_N + n * 16 + l15] = v;
        dot += v * ((r < B_N) ? av0[n] : av1[n]);
      }
      #pragma unroll
      for (int s = 1; s < 16; s <<= 1) dot += __shfl_xor(dot, s, 64);
      if (ok && l15 == 0) {
        if (r < B_N) p[r] = dot;
        else q[r - B_N] = dot;
      }
    }
  }
}

// per-node attention + weighted aggregation; one wave per node (K=10 edges each)
__launch_bounds__(256)
__global__ void aggregate(const float* __restrict__ h, const float* __restrict__ p,
                          const float* __restrict__ q, const int* __restrict__ edst,
                          float* __restrict__ hp) {
  int node = blockIdx.x * 4 + (threadIdx.x >> 6);
  int lane = threadIdx.x & 63;
  if (node >= B_N) return;
  float pi = p[node];
  float a0 = 0.f, a1 = 0.f, sum = 0.f;
  #pragma unroll
  for (int k = 0; k < K_N; k++) {
    int dst = edst[node * K_N + k];
    float s  = pi + q[dst];
    float le = (s >= 0.f) ? s : 0.2f * s;
    float ee = expf(-le);
    sum += ee;
    float2 hv = reinterpret_cast<const float2*>(h + (size_t)(B_N + dst) * D_N)[lane];
    a0 += ee * hv.x;
    a1 += ee * hv.y;
  }
  float inv = 1.f / sum;
  float r0 = a0 * inv, r1 = a1 * inv;
  if (!isfinite(r0)) r0 = 0.f;
  if (!isfinite(r1)) r1 = 0.f;
  reinterpret_cast<float2*>(hp + (size_t)node * D_N)[lane] = make_float2(r0, r1);
}

// GEMM2: out[100000][128] = relu(concat(fb, hp, nf) @ Wd)
__launch_bounds__(256, 2)
__global__ void gemm2(const float* __restrict__ fb, const float* __restrict__ hp,
                      const float* __restrict__ nf, const ushort* __restrict__ Wdt,
                      float* __restrict__ out) {
  __shared__ ushort As[128 * LDS_STRIDE];
  const int tid  = threadIdx.x;
  const int lane = tid & 63;
  const int wv   = tid >> 6;
  const int row0 = blockIdx.x * 128;
  const int l15 = lane & 15;
  const int l4  = lane >> 4;

  f32x4 acc[2][8];
  #pragma unroll
  for (int m = 0; m < 2; m++)
    #pragma unroll
    for (int n = 0; n < 8; n++) acc[m][n] = (f32x4)0.0f;

  for (int kt = 0; kt < K2 / BK; ++kt) {
    const int k0 = kt * BK;
    const float* src;
    int ld, koff;
    if (k0 < 512)       { src = fb; ld = 512; koff = k0; }
    else if (k0 < 640)  { src = hp; ld = 128; koff = k0 - 512; }
    else                { src = nf; ld = 512; koff = k0 - 640; }
    __syncthreads();
    #pragma unroll
    for (int i = 0; i < 4; ++i) {
      int lin = tid + i * 256;
      int r   = lin >> 3;
      int qd  = lin & 7;
      int gr  = row0 + r;
      ushort4 ov;
      if (gr < B_N) {
        float4 v = *reinterpret_cast<const float4*>(src + (size_t)gr * ld + koff + qd * 4);
        ov.x = f2bf(v.x); ov.y = f2bf(v.y); ov.z = f2bf(v.z); ov.w = f2bf(v.w);
      } else {
        ov = make_ushort4(0, 0, 0, 0);
      }
      *reinterpret_cast<ushort4*>(&As[r * LDS_STRIDE + qd * 4]) = ov;
    }
    __syncthreads();

    bf16x8 af[2];
    #pragma unroll
    for (int m = 0; m < 2; m++) {
      int r = wv * 32 + m * 16 + l15;
      af[m] = *reinterpret_cast<const bf16x8*>(&As[r * LDS_STRIDE + l4 * 8]);
    }
    #pragma unroll
    for (int n = 0; n < 8; n++) {
      int c = n * 16 + l15;
      bf16x8 bfr = *reinterpret_cast<const bf16x8*>(Wdt + (size_t)c * K2 + k0 + l4 * 8);
      acc[0][n] = __builtin_amdgcn_mfma_f32_16x16x32_bf16(af[0], bfr, acc[0][n], 0, 0, 0);
      acc[1][n] = __builtin_amdgcn_mfma_f32_16x16x32_bf16(af[1], bfr, acc[1][n], 0, 0, 0);
    }
  }

  #pragma unroll
  for (int m = 0; m < 2; m++) {
    #pragma unroll
    for (int j = 0; j < 4; j++) {
      int r = row0 + wv * 32 + m * 16 + l4 * 4 + j;
      if (r < B_N) {
        #pragma unroll
        for (int n = 0; n < 8; n++)
          out[(size_t)r * D_N + n * 16 + l15] = fmaxf(acc[m][n][j], 0.0f);
      }
    }
  }
}

extern "C" void kernel_launch(void* const* d_in, const int* in_sizes, int n_in,
                              void* d_out, int out_size, void* d_ws, size_t ws_size,
                              hipStream_t stream) {
  const float* fb = (const float*)d_in[0];   // feats_batch [B,512]
  const float* fn = (const float*)d_in[1];   // feats_neigh [U,512]
  const float* nf = (const float*)d_in[2];   // neigh_feats [B,512]
  const float* W  = (const float*)d_in[3];   // [512,128]
  const float* a  = (const float*)d_in[4];   // [1,256]
  const float* Wd = (const float*)d_in[5];   // [1152,128]
  // d_in[6] = edge_src: structurally e/K (repeat(arange(B),K)) — not needed
  const int* edst = (const int*)d_in[7];     // [E]
  float* out = (float*)d_out;

  char* ws = (char*)d_ws;
  float*  h   = (float*)(ws);                  // 150000*128*4 = 76,800,000
  float*  hp  = (float*)(ws + 76800000);       // 100000*128*4 = 51,200,000
  float*  p   = (float*)(ws + 128000000);      // 100000*4
  float*  q   = (float*)(ws + 128400000);      // 50000*4
  ushort* Wt  = (ushort*)(ws + 128600000);     // 128*512*2
  ushort* Wdt = (ushort*)(ws + 128731072);     // 128*1152*2

  prep_transpose_bf16<<<(K1 * D_N + 255) / 256, 256, 0, stream>>>(W, Wt, K1, D_N);
  prep_transpose_bf16<<<(K2 * D_N + 255) / 256, 256, 0, stream>>>(Wd, Wdt, K2, D_N);
  gemm1<<<(M1 + 127) / 128, 256, 0, stream>>>(fb, fn, Wt, a, h, p, q);
  aggregate<<<(B_N + 3) / 4, 256, 0, stream>>>(h, p, q, edst, hp);
  gemm2<<<(B_N + 127) / 128, 256, 0, stream>>>(fb, hp, nf, Wdt, out);
}

// Round 2
// 639.874 us; speedup vs baseline: 1.3018x; 1.3018x over previous
//
#include <hip/hip_runtime.h>

#define B_N 100000
#define U_N 50000
#define F_N 512
#define D_N 128
#define K_N 10
#define M1  150000   // B_N + U_N
#define K1  512
#define K2  1152     // 2F + D

typedef __attribute__((ext_vector_type(8))) short bf16x8;
typedef __attribute__((ext_vector_type(4))) float f32x4;

static __device__ __forceinline__ ushort f2bf(float f) {
  union { float f; unsigned u; } x; x.f = f;
  unsigned r = x.u + 0x7fffu + ((x.u >> 16) & 1u);
  return (ushort)(r >> 16);
}

static __device__ __forceinline__ bf16x8 pack8(float4 lo, float4 hi) {
  bf16x8 r;
  r[0] = (short)f2bf(lo.x); r[1] = (short)f2bf(lo.y);
  r[2] = (short)f2bf(lo.z); r[3] = (short)f2bf(lo.w);
  r[4] = (short)f2bf(hi.x); r[5] = (short)f2bf(hi.y);
  r[6] = (short)f2bf(hi.z); r[7] = (short)f2bf(hi.w);
  return r;
}

// Build fragment-ordered bf16 B-matrix: frag (kt,n,lane) holds 8 bf16 of
// W[k=kt*32+(lane>>4)*8 + j][col=n*16+(lane&15)]. One wave's (kt,n) B-frag
// is then a single contiguous 1KB global read.
__global__ void prep_frag(const float* __restrict__ Wsrc, ushort* __restrict__ dst, int KTOT) {
  int t = blockIdx.x * 256 + threadIdx.x;
  int total = (KTOT / 32) * 8 * 64;
  if (t >= total) return;
  int lane = t & 63;
  int fid  = t >> 6;
  int n  = fid & 7;
  int kt = fid >> 3;
  int col = n * 16 + (lane & 15);
  int k0  = kt * 32 + (lane >> 4) * 8;
  bf16x8 r;
  #pragma unroll
  for (int j = 0; j < 8; j++) r[j] = (short)f2bf(Wsrc[(size_t)(k0 + j) * D_N + col]);
  *reinterpret_cast<bf16x8*>(dst + (size_t)t * 8) = r;
}

// GEMM1: per-wave 32 rows, no LDS, no barriers. A: global fp32 -> bf16 regs.
// B: fragment-ordered global (L2-resident). Batch rows -> p only (no h store);
// neigh rows -> h (bf16) + q.
__launch_bounds__(256)
__global__ void gemm1(const float* __restrict__ fb, const float* __restrict__ fn,
                      const ushort* __restrict__ Wtf, const float* __restrict__ avec,
                      ushort* __restrict__ hnb, float* __restrict__ p,
                      float* __restrict__ q) {
  const int tid  = threadIdx.x;
  const int lane = tid & 63;
  const int wave_id = blockIdx.x * 4 + (tid >> 6);
  const size_t r0 = (size_t)wave_id * 32;
  if (r0 >= M1) return;
  const int l15 = lane & 15;
  const int l4  = lane >> 4;
  const bool is_batch = (r0 < B_N);   // B_N%32==0 -> wave-uniform

  f32x4 acc[2][8];
  #pragma unroll
  for (int m = 0; m < 2; m++)
    #pragma unroll
    for (int n = 0; n < 8; n++) acc[m][n] = (f32x4)0.0f;

  const float* base = is_batch ? fb : fn;
  const size_t roff = is_batch ? r0 : (r0 - B_N);
  const size_t maxr = is_batch ? (B_N - 1) : (U_N - 1);
  size_t ra = roff + l15;       if (ra > maxr) ra = maxr;
  size_t rb = roff + 16 + l15;  if (rb > maxr) rb = maxr;
  const float* aptr0 = base + ra * F_N;
  const float* aptr1 = base + rb * F_N;

  for (int kt = 0; kt < K1 / 32; ++kt) {
    const int koff = kt * 32 + l4 * 8;
    float4 a00 = *reinterpret_cast<const float4*>(aptr0 + koff);
    float4 a01 = *reinterpret_cast<const float4*>(aptr0 + koff + 4);
    float4 a10 = *reinterpret_cast<const float4*>(aptr1 + koff);
    float4 a11 = *reinterpret_cast<const float4*>(aptr1 + koff + 4);
    bf16x8 bfr[8];
    #pragma unroll
    for (int n = 0; n < 8; n++)
      bfr[n] = *reinterpret_cast<const bf16x8*>(Wtf + ((size_t)(kt * 8 + n) * 64 + lane) * 8);
    bf16x8 af0 = pack8(a00, a01);
    bf16x8 af1 = pack8(a10, a11);
    #pragma unroll
    for (int n = 0; n < 8; n++) {
      acc[0][n] = __builtin_amdgcn_mfma_f32_16x16x32_bf16(af0, bfr[n], acc[0][n], 0, 0, 0);
      acc[1][n] = __builtin_amdgcn_mfma_f32_16x16x32_bf16(af1, bfr[n], acc[1][n], 0, 0, 0);
    }
  }

  if (is_batch) {
    float av[8];
    #pragma unroll
    for (int n = 0; n < 8; n++) av[n] = avec[n * 16 + l15];
    #pragma unroll
    for (int m = 0; m < 2; m++) {
      #pragma unroll
      for (int j = 0; j < 4; j++) {
        size_t r = r0 + m * 16 + l4 * 4 + j;
        float dot = 0.f;
        #pragma unroll
        for (int n = 0; n < 8; n++) dot += acc[m][n][j] * av[n];
        #pragma unroll
        for (int s = 1; s < 16; s <<= 1) dot += __shfl_xor(dot, s, 64);
        if (l15 == 0) p[r] = dot;
      }
    }
  } else {
    float av[8];
    #pragma unroll
    for (int n = 0; n < 8; n++) av[n] = avec[D_N + n * 16 + l15];
    #pragma unroll
    for (int m = 0; m < 2; m++) {
      #pragma unroll
      for (int j = 0; j < 4; j++) {
        size_t u = (r0 - B_N) + m * 16 + l4 * 4 + j;
        bool ok = u < U_N;
        float dot = 0.f;
        #pragma unroll
        for (int n = 0; n < 8; n++) {
          float v = acc[m][n][j];
          if (ok) hnb[u * D_N + n * 16 + l15] = f2bf(v);
          dot += v * av[n];
        }
        #pragma unroll
        for (int s = 1; s < 16; s <<= 1) dot += __shfl_xor(dot, s, 64);
        if (ok && l15 == 0) q[u] = dot;
      }
    }
  }
}

// one wave per node; h rows are bf16 (256B contiguous gather); hp written bf16
__launch_bounds__(256)
__global__ void aggregate(const ushort* __restrict__ hnb, const float* __restrict__ p,
                          const float* __restrict__ q, const int* __restrict__ edst,
                          ushort* __restrict__ hp) {
  int node = blockIdx.x * 4 + (threadIdx.x >> 6);
  int lane = threadIdx.x & 63;
  if (node >= B_N) return;
  float pi = p[node];
  int dsts[K_N];
  #pragma unroll
  for (int k = 0; k < K_N; k++) dsts[k] = edst[node * K_N + k];
  float a0 = 0.f, a1 = 0.f, sum = 0.f;
  #pragma unroll
  for (int k = 0; k < K_N; k++) {
    int dst = dsts[k];
    float s  = pi + q[dst];
    float le = (s >= 0.f) ? s : 0.2f * s;
    float ee = expf(-le);
    sum += ee;
    unsigned hv = *reinterpret_cast<const unsigned*>(hnb + (size_t)dst * D_N + lane * 2);
    float h0 = __uint_as_float((hv & 0xffffu) << 16);
    float h1 = __uint_as_float(hv & 0xffff0000u);
    a0 += ee * h0;
    a1 += ee * h1;
  }
  float inv = 1.f / sum;
  float r0v = a0 * inv, r1v = a1 * inv;
  if (!isfinite(r0v)) r0v = 0.f;
  if (!isfinite(r1v)) r1v = 0.f;
  unsigned o = (unsigned)f2bf(r0v) | ((unsigned)f2bf(r1v) << 16);
  *reinterpret_cast<unsigned*>(hp + (size_t)node * D_N + lane * 2) = o;
}

// GEMM2: out = relu([fb | hp | nf] @ Wd); same barrier-free per-wave design.
__launch_bounds__(256)
__global__ void gemm2(const float* __restrict__ fb, const ushort* __restrict__ hp,
                      const float* __restrict__ nf, const ushort* __restrict__ Wdf,
                      float* __restrict__ out) {
  const int tid  = threadIdx.x;
  const int lane = tid & 63;
  const int wave_id = blockIdx.x * 4 + (tid >> 6);
  const size_t r0 = (size_t)wave_id * 32;
  if (r0 >= B_N) return;   // B_N%32==0 -> all waves full
  const int l15 = lane & 15;
  const int l4  = lane >> 4;

  f32x4 acc[2][8];
  #pragma unroll
  for (int m = 0; m < 2; m++)
    #pragma unroll
    for (int n = 0; n < 8; n++) acc[m][n] = (f32x4)0.0f;

  // region 1: fb, global kt 0..15
  {
    const float* aptr0 = fb + (r0 + l15) * F_N;
    const float* aptr1 = fb + (r0 + 16 + l15) * F_N;
    for (int kt = 0; kt < 16; ++kt) {
      const int koff = kt * 32 + l4 * 8;
      float4 a00 = *reinterpret_cast<const float4*>(aptr0 + koff);
      float4 a01 = *reinterpret_cast<const float4*>(aptr0 + koff + 4);
      float4 a10 = *reinterpret_cast<const float4*>(aptr1 + koff);
      float4 a11 = *reinterpret_cast<const float4*>(aptr1 + koff + 4);
      bf16x8 bfr[8];
      #pragma unroll
      for (int n = 0; n < 8; n++)
        bfr[n] = *reinterpret_cast<const bf16x8*>(Wdf + ((size_t)(kt * 8 + n) * 64 + lane) * 8);
      bf16x8 af0 = pack8(a00, a01);
      bf16x8 af1 = pack8(a10, a11);
      #pragma unroll
      for (int n = 0; n < 8; n++) {
        acc[0][n] = __builtin_amdgcn_mfma_f32_16x16x32_bf16(af0, bfr[n], acc[0][n], 0, 0, 0);
        acc[1][n] = __builtin_amdgcn_mfma_f32_16x16x32_bf16(af1, bfr[n], acc[1][n], 0, 0, 0);
      }
    }
  }
  // region 2: hp (bf16, direct frags), global kt 16..19
  {
    const ushort* h0p = hp + (r0 + l15) * D_N;
    const ushort* h1p = hp + (r0 + 16 + l15) * D_N;
    for (int kt = 0; kt < 4; ++kt) {
      const int koff = kt * 32 + l4 * 8;
      bf16x8 af0 = *reinterpret_cast<const bf16x8*>(h0p + koff);
      bf16x8 af1 = *reinterpret_cast<const bf16x8*>(h1p + koff);
      bf16x8 bfr[8];
      #pragma unroll
      for (int n = 0; n < 8; n++)
        bfr[n] = *reinterpret_cast<const bf16x8*>(Wdf + ((size_t)((16 + kt) * 8 + n) * 64 + lane) * 8);
      #pragma unroll
      for (int n = 0; n < 8; n++) {
        acc[0][n] = __builtin_amdgcn_mfma_f32_16x16x32_bf16(af0, bfr[n], acc[0][n], 0, 0, 0);
        acc[1][n] = __builtin_amdgcn_mfma_f32_16x16x32_bf16(af1, bfr[n], acc[1][n], 0, 0, 0);
      }
    }
  }
  // region 3: nf, global kt 20..35
  {
    const float* aptr0 = nf + (r0 + l15) * F_N;
    const float* aptr1 = nf + (r0 + 16 + l15) * F_N;
    for (int kt = 0; kt < 16; ++kt) {
      const int koff = kt * 32 + l4 * 8;
      float4 a00 = *reinterpret_cast<const float4*>(aptr0 + koff);
      float4 a01 = *reinterpret_cast<const float4*>(aptr0 + koff + 4);
      float4 a10 = *reinterpret_cast<const float4*>(aptr1 + koff);
      float4 a11 = *reinterpret_cast<const float4*>(aptr1 + koff + 4);
      bf16x8 bfr[8];
      #pragma unroll
      for (int n = 0; n < 8; n++)
        bfr[n] = *reinterpret_cast<const bf16x8*>(Wdf + ((size_t)((20 + kt) * 8 + n) * 64 + lane) * 8);
      bf16x8 af0 = pack8(a00, a01);
      bf16x8 af1 = pack8(a10, a11);
      #pragma unroll
      for (int n = 0; n < 8; n++) {
        acc[0][n] = __builtin_amdgcn_mfma_f32_16x16x32_bf16(af0, bfr[n], acc[0][n], 0, 0, 0);
        acc[1][n] = __builtin_amdgcn_mfma_f32_16x16x32_bf16(af1, bfr[n], acc[1][n], 0, 0, 0);
      }
    }
  }

  #pragma unroll
  for (int m = 0; m < 2; m++) {
    #pragma unroll
    for (int j = 0; j < 4; j++) {
      size_t r = r0 + m * 16 + l4 * 4 + j;
      #pragma unroll
      for (int n = 0; n < 8; n++)
        out[r * D_N + n * 16 + l15] = fmaxf(acc[m][n][j], 0.0f);
    }
  }
}

extern "C" void kernel_launch(void* const* d_in, const int* in_sizes, int n_in,
                              void* d_out, int out_size, void* d_ws, size_t ws_size,
                              hipStream_t stream) {
  const float* fb = (const float*)d_in[0];   // feats_batch [B,512]
  const float* fn = (const float*)d_in[1];   // feats_neigh [U,512]
  const float* nf = (const float*)d_in[2];   // neigh_feats [B,512]
  const float* W  = (const float*)d_in[3];   // [512,128]
  const float* a  = (const float*)d_in[4];   // [1,256]
  const float* Wd = (const float*)d_in[5];   // [1152,128]
  // d_in[6] = edge_src: structurally repeat(arange(B),K) — not needed
  const int* edst = (const int*)d_in[7];     // [E]
  float* out = (float*)d_out;

  char* ws = (char*)d_ws;
  ushort* hnb = (ushort*)(ws);               // 50000*128*2  = 12,800,000
  ushort* hp  = (ushort*)(ws + 12800000);    // 100000*128*2 = 25,600,000
  float*  p   = (float*) (ws + 38400000);    // 100000*4
  float*  q   = (float*) (ws + 38800000);    // 50000*4
  ushort* Wtf = (ushort*)(ws + 39000000);    // 16*8*64*8*2  = 131,072
  ushort* Wdf = (ushort*)(ws + 39131072);    // 36*8*64*8*2  = 294,912

  prep_frag<<<(16 * 8 * 64 + 255) / 256, 256, 0, stream>>>(W, Wtf, K1);
  prep_frag<<<(36 * 8 * 64 + 255) / 256, 256, 0, stream>>>(Wd, Wdf, K2);
  gemm1<<<((M1 + 31) / 32 + 3) / 4, 256, 0, stream>>>(fb, fn, Wtf, a, hnb, p, q);
  aggregate<<<(B_N + 3) / 4, 256, 0, stream>>>(hnb, p, q, edst, hp);
  gemm2<<<((B_N / 32) + 3) / 4, 256, 0, stream>>>(fb, hp, nf, Wdf, out);
}